// Round 1
// baseline (881.062 us; speedup 1.0000x reference)
//
#include <hip/hip_runtime.h>
#include <math.h>

#define NN 20000        // nodes
#define NE 320000       // edges
#define HID 128
#define IN_DIM 192
#define NODE_IN 64

__device__ __forceinline__ float sigmoidf(float x) {
    return __builtin_amdgcn_rcpf(1.0f + __expf(-x));
}

// ---------------- generic fp32 GEMM: C[M,N] = act(A[M,K] @ B[K,N] (+bias)) ----------
// 64x64 tile, 128 threads, 4 rows x 8 cols per thread (32 FMA per 48 LDS bytes).
template<bool CONCAT_A, bool RELU, bool BIAS>
__launch_bounds__(128)
__global__ void gemm_f32(const float* __restrict__ A0, const float* __restrict__ A1,
                         const float* __restrict__ B, const float* __restrict__ bias,
                         float* __restrict__ C, int M, int N, int K)
{
    __shared__ float As[16][68];
    __shared__ float Bs[16][68];
    const int tid = threadIdx.x;
    const int tx = tid & 7;        // col octet: cols tx*8 .. tx*8+7
    const int ty = tid >> 3;       // row quad: rows ty*4 .. ty*4+3   (ty in [0,16))
    const int m0 = blockIdx.x * 64;
    const int n0 = blockIdx.y * 64;
    float acc[4][8] = {};

    for (int k0 = 0; k0 < K; k0 += 16) {
        #pragma unroll
        for (int i = 0; i < 8; ++i) {
            int g = tid + i * 128;
            int r = g >> 4;
            int c = g & 15;
            int mr = m0 + r;
            int k  = k0 + c;
            float v = 0.f;
            if (mr < M) {
                if (CONCAT_A) v = (k < 128) ? A0[mr * 128 + k] : A1[mr * 128 + (k - 128)];
                else          v = A0[mr * K + k];
            }
            As[c][r] = v;
        }
        #pragma unroll
        for (int i = 0; i < 8; ++i) {
            int g = tid + i * 128;
            int kr = g >> 6;
            int c  = g & 63;
            Bs[kr][c] = B[(k0 + kr) * N + (n0 + c)];
        }
        __syncthreads();
        #pragma unroll
        for (int kk = 0; kk < 16; ++kk) {
            float4 a  = *(const float4*)&As[kk][ty * 4];
            float4 b0 = *(const float4*)&Bs[kk][tx * 8];
            float4 b1 = *(const float4*)&Bs[kk][tx * 8 + 4];
            float av[4] = {a.x, a.y, a.z, a.w};
            float bv[8] = {b0.x, b0.y, b0.z, b0.w, b1.x, b1.y, b1.z, b1.w};
            #pragma unroll
            for (int i = 0; i < 4; ++i)
                #pragma unroll
                for (int j = 0; j < 8; ++j)
                    acc[i][j] = fmaf(av[i], bv[j], acc[i][j]);
        }
        __syncthreads();
    }
    #pragma unroll
    for (int i = 0; i < 4; ++i) {
        int row = m0 + ty * 4 + i;
        if (row < M) {
            int col = n0 + tx * 8;
            float4 v0, v1;
            v0.x = acc[i][0]; v0.y = acc[i][1]; v0.z = acc[i][2]; v0.w = acc[i][3];
            v1.x = acc[i][4]; v1.y = acc[i][5]; v1.z = acc[i][6]; v1.w = acc[i][7];
            if (BIAS) {
                float4 bb0 = *(const float4*)&bias[col];
                float4 bb1 = *(const float4*)&bias[col + 4];
                v0.x += bb0.x; v0.y += bb0.y; v0.z += bb0.z; v0.w += bb0.w;
                v1.x += bb1.x; v1.y += bb1.y; v1.z += bb1.z; v1.w += bb1.w;
            }
            if (RELU) {
                v0.x = fmaxf(v0.x, 0.f); v0.y = fmaxf(v0.y, 0.f);
                v0.z = fmaxf(v0.z, 0.f); v0.w = fmaxf(v0.w, 0.f);
                v1.x = fmaxf(v1.x, 0.f); v1.y = fmaxf(v1.y, 0.f);
                v1.z = fmaxf(v1.z, 0.f); v1.w = fmaxf(v1.w, 0.f);
            }
            *(float4*)&C[row * N + col]     = v0;
            *(float4*)&C[row * N + col + 4] = v1;
        }
    }
}

// -------- node weight: nw[n] = sigmoid(dot(h[n,:128], W2) + b2), one wave per node -----
__global__ void nw_kernel(const float* __restrict__ h, const float* __restrict__ W2,
                          const float* __restrict__ b2, float* __restrict__ nw)
{
    int n = blockIdx.x * 4 + (threadIdx.x >> 6);
    int l = threadIdx.x & 63;
    if (n >= NN) return;
    float p = h[n * 128 + l] * W2[l] + h[n * 128 + 64 + l] * W2[64 + l];
    #pragma unroll
    for (int off = 32; off > 0; off >>= 1)
        p += __shfl_down(p, off, 64);
    if (l == 0) nw[n] = sigmoidf(p + b2[0]);
}

// -------- degree histogram over 2E incidence slots --------------------------------------
__global__ void deg_kernel(const int* __restrict__ ei, int* __restrict__ deg)
{
    int s = blockIdx.x * blockDim.x + threadIdx.x;
    if (s >= 2 * NE) return;
    atomicAdd(&deg[ei[s]], 1);
}

// -------- Dinv[j] = 1 / (nw[u_j] + nw[v_j]) ---------------------------------------------
__global__ void dinv_kernel(const int* __restrict__ ei, const float* __restrict__ nw,
                            float* __restrict__ Dinv)
{
    int j = blockIdx.x * blockDim.x + threadIdx.x;
    if (j >= NE) return;
    float d = nw[ei[j]] + nw[ei[NE + j]];
    Dinv[j] = __builtin_amdgcn_rcpf(d);
}

// -------- single-block exclusive scan of deg -> off; also Binv = 1/deg ------------------
__global__ void scan_kernel(const int* __restrict__ deg, int* __restrict__ off,
                            float* __restrict__ Binv)
{
    __shared__ int part[1024];
    int t = threadIdx.x;
    const int C = (NN + 1023) / 1024;   // 20
    int base = t * C;
    int s = 0;
    for (int i = 0; i < C; ++i) {
        int idx = base + i;
        if (idx < NN) s += deg[idx];
    }
    part[t] = s;
    __syncthreads();
    for (int o = 1; o < 1024; o <<= 1) {
        int v = (t >= o) ? part[t - o] : 0;
        __syncthreads();
        part[t] += v;
        __syncthreads();
    }
    int excl = (t == 0) ? 0 : part[t - 1];
    for (int i = 0; i < C; ++i) {
        int idx = base + i;
        if (idx < NN) {
            off[idx] = excl;
            int d = deg[idx];
            excl += d;
            Binv[idx] = (d > 0) ? 1.0f / (float)d : 0.0f;
        }
    }
    if (t == 0) off[NN] = part[1023];
}

// -------- CSR fill with precomputed other-endpoint --------------------------------------
__global__ void fill_kernel(const int* __restrict__ ei, const int* __restrict__ off,
                            int* __restrict__ cur, int* __restrict__ csr_j,
                            int* __restrict__ csr_o)
{
    int s = blockIdx.x * blockDim.x + threadIdx.x;
    if (s >= 2 * NE) return;
    int n = ei[s];
    int j = (s < NE) ? s : s - NE;
    int o = ei[(s < NE) ? s + NE : s - NE];
    int p = atomicAdd(&cur[n], 1);
    int w = off[n] + p;
    csr_j[w] = j;
    csr_o[w] = o;
}

// -------- agg0[n,c] = Binv[n] * sum_{edges j at n} er0[j,c] -----------------------------
// er0[j] = [edge_rep[j] (192) | 0.5*(nf[n]+nf[o_j]) (64)]
// float4 layout: threads 0..191 = er part (48 f4-groups x 4 slots, waves 0-2 uniform-er),
// threads 192..255 = nf part (16 f4-groups x 4 slots, wave 3 uniform-nf).
// Each wave gathers a full row per load instruction; slot partials reduced via LDS.
__launch_bounds__(256)
__global__ void agg0_kernel(const int* __restrict__ csr_j, const int* __restrict__ csr_o,
                            const int* __restrict__ off, const float* __restrict__ Binv,
                            const float* __restrict__ er, const float* __restrict__ nf,
                            float* __restrict__ agg0)
{
    __shared__ int sh_j[256];
    __shared__ int sh_o[256];
    __shared__ float4 sh_acc[256];
    const int n = blockIdx.x;
    const int tid = threadIdx.x;
    const bool is_er = tid < 192;
    int grp, slot;
    if (is_er) { grp = tid % 48;          slot = tid / 48; }
    else       { grp = (tid - 192) & 15;  slot = (tid - 192) >> 4; }
    const int s0 = off[n], s1 = off[n + 1];
    float4 acc = make_float4(0.f, 0.f, 0.f, 0.f);

    for (int base = s0; base < s1; base += 256) {
        int cnt = min(256, s1 - base);
        if (tid < cnt) {
            sh_j[tid] = csr_j[base + tid];
            sh_o[tid] = csr_o[base + tid];
        }
        __syncthreads();
        if (is_er) {
            int t = slot;
            for (; t + 4 < cnt; t += 8) {
                float4 v0 = *(const float4*)&er[(size_t)sh_j[t] * 192 + grp * 4];
                float4 v1 = *(const float4*)&er[(size_t)sh_j[t + 4] * 192 + grp * 4];
                acc.x += v0.x + v1.x; acc.y += v0.y + v1.y;
                acc.z += v0.z + v1.z; acc.w += v0.w + v1.w;
            }
            if (t < cnt) {
                float4 v = *(const float4*)&er[(size_t)sh_j[t] * 192 + grp * 4];
                acc.x += v.x; acc.y += v.y; acc.z += v.z; acc.w += v.w;
            }
        } else {
            int t = slot;
            for (; t + 4 < cnt; t += 8) {
                float4 v0 = *(const float4*)&nf[(size_t)sh_o[t] * 64 + grp * 4];
                float4 v1 = *(const float4*)&nf[(size_t)sh_o[t + 4] * 64 + grp * 4];
                acc.x += v0.x + v1.x; acc.y += v0.y + v1.y;
                acc.z += v0.z + v1.z; acc.w += v0.w + v1.w;
            }
            if (t < cnt) {
                float4 v = *(const float4*)&nf[(size_t)sh_o[t] * 64 + grp * 4];
                acc.x += v.x; acc.y += v.y; acc.z += v.z; acc.w += v.w;
            }
        }
        __syncthreads();
    }

    sh_acc[tid] = acc;
    __syncthreads();
    if (tid < 64) {
        float4 tot;
        if (tid < 48) {
            float4 p0 = sh_acc[tid], p1 = sh_acc[tid + 48];
            float4 p2 = sh_acc[tid + 96], p3 = sh_acc[tid + 144];
            tot.x = (p0.x + p1.x) + (p2.x + p3.x);
            tot.y = (p0.y + p1.y) + (p2.y + p3.y);
            tot.z = (p0.z + p1.z) + (p2.z + p3.z);
            tot.w = (p0.w + p1.w) + (p2.w + p3.w);
        } else {
            int b = 192 + (tid - 48);
            float4 p0 = sh_acc[b], p1 = sh_acc[b + 16];
            float4 p2 = sh_acc[b + 32], p3 = sh_acc[b + 48];
            tot.x = (p0.x + p1.x) + (p2.x + p3.x);
            tot.y = (p0.y + p1.y) + (p2.y + p3.y);
            tot.z = (p0.z + p1.z) + (p2.z + p3.z);
            tot.w = (p0.w + p1.w) + (p2.w + p3.w);
            float degf = (float)(s1 - s0);
            float4 nfn = *(const float4*)&nf[(size_t)n * 64 + (tid - 48) * 4];
            tot.x = 0.5f * (tot.x + degf * nfn.x);
            tot.y = 0.5f * (tot.y + degf * nfn.y);
            tot.z = 0.5f * (tot.z + degf * nfn.z);
            tot.w = 0.5f * (tot.w + degf * nfn.w);
        }
        float bi = Binv[n];
        tot.x *= bi; tot.y *= bi; tot.z *= bi; tot.w *= bi;
        *(float4*)&agg0[(size_t)n * 256 + tid * 4] = tot;
    }
}

// -------- agg1[n,c] = Binv[n] * sum_j sigmoid(Dinv[j]*(e1[n,c]+e1[o_j,c]) + b1[c]) ------
// float4: cg = tid&63 covers 256 channels, slot = tid>>6 (one wave per slot).
// Each wave reads a full 1KB e1 row per load instruction.
__launch_bounds__(256)
__global__ void agg1_kernel(const int* __restrict__ csr_j, const int* __restrict__ csr_o,
                            const int* __restrict__ off, const float* __restrict__ Binv,
                            const float* __restrict__ Dinv, const float* __restrict__ e1,
                            const float* __restrict__ b1, float* __restrict__ agg1)
{
    __shared__ int sh_o[256];
    __shared__ float sh_d[256];
    __shared__ float4 sh_acc[256];
    const int n = blockIdx.x;
    const int tid = threadIdx.x;
    const int cg = tid & 63;
    const int slot = tid >> 6;
    const int s0 = off[n], s1 = off[n + 1];
    float4 myv = *(const float4*)&e1[(size_t)n * 256 + cg * 4];
    float4 bc  = *(const float4*)&b1[cg * 4];
    float4 acc = make_float4(0.f, 0.f, 0.f, 0.f);

    for (int base = s0; base < s1; base += 256) {
        int cnt = min(256, s1 - base);
        if (tid < cnt) {
            int jj = csr_j[base + tid];
            sh_o[tid] = csr_o[base + tid];
            sh_d[tid] = Dinv[jj];
        }
        __syncthreads();
        int t = slot;
        for (; t + 4 < cnt; t += 8) {
            int o0 = sh_o[t], o1 = sh_o[t + 4];
            float d0 = sh_d[t], d1 = sh_d[t + 4];
            float4 v0 = *(const float4*)&e1[(size_t)o0 * 256 + cg * 4];
            float4 v1 = *(const float4*)&e1[(size_t)o1 * 256 + cg * 4];
            acc.x += sigmoidf(fmaf(d0, myv.x + v0.x, bc.x));
            acc.y += sigmoidf(fmaf(d0, myv.y + v0.y, bc.y));
            acc.z += sigmoidf(fmaf(d0, myv.z + v0.z, bc.z));
            acc.w += sigmoidf(fmaf(d0, myv.w + v0.w, bc.w));
            acc.x += sigmoidf(fmaf(d1, myv.x + v1.x, bc.x));
            acc.y += sigmoidf(fmaf(d1, myv.y + v1.y, bc.y));
            acc.z += sigmoidf(fmaf(d1, myv.z + v1.z, bc.z));
            acc.w += sigmoidf(fmaf(d1, myv.w + v1.w, bc.w));
        }
        if (t < cnt) {
            int o0 = sh_o[t];
            float d0 = sh_d[t];
            float4 v0 = *(const float4*)&e1[(size_t)o0 * 256 + cg * 4];
            acc.x += sigmoidf(fmaf(d0, myv.x + v0.x, bc.x));
            acc.y += sigmoidf(fmaf(d0, myv.y + v0.y, bc.y));
            acc.z += sigmoidf(fmaf(d0, myv.z + v0.z, bc.z));
            acc.w += sigmoidf(fmaf(d0, myv.w + v0.w, bc.w));
        }
        __syncthreads();
    }

    sh_acc[tid] = acc;
    __syncthreads();
    if (tid < 64) {
        float4 p1 = sh_acc[tid + 64], p2 = sh_acc[tid + 128], p3 = sh_acc[tid + 192];
        float bi = Binv[n];
        float4 outv;
        outv.x = ((acc.x + p1.x) + (p2.x + p3.x)) * bi;
        outv.y = ((acc.y + p1.y) + (p2.y + p3.y)) * bi;
        outv.z = ((acc.z + p1.z) + (p2.z + p3.z)) * bi;
        outv.w = ((acc.w + p1.w) + (p2.w + p3.w)) * bi;
        *(float4*)&agg1[(size_t)n * 256 + tid * 4] = outv;
    }
}

// -------- final: out[j,c] = sigmoid(Dinv[j]*(e2[u,c]+e2[v,c]) + b2[c]) ------------------
// float4: 8 edges per 256-thread block, 32 lanes x f4 = 128 channels per edge.
__global__ void out_kernel(const float* __restrict__ e2, const float* __restrict__ Dinv,
                           const int* __restrict__ ei, const float* __restrict__ b2,
                           float* __restrict__ out)
{
    int j = blockIdx.x * 8 + (threadIdx.x >> 5);
    int cg = threadIdx.x & 31;
    int u = ei[j], v = ei[NE + j];
    float d = Dinv[j];
    float4 a  = *(const float4*)&e2[(size_t)u * 128 + cg * 4];
    float4 b  = *(const float4*)&e2[(size_t)v * 128 + cg * 4];
    float4 bb = *(const float4*)&b2[cg * 4];
    float4 r;
    r.x = sigmoidf(fmaf(d, a.x + b.x, bb.x));
    r.y = sigmoidf(fmaf(d, a.y + b.y, bb.y));
    r.z = sigmoidf(fmaf(d, a.z + b.z, bb.z));
    r.w = sigmoidf(fmaf(d, a.w + b.w, bb.w));
    *(float4*)&out[(size_t)j * 128 + cg * 4] = r;
}

extern "C" void kernel_launch(void* const* d_in, const int* in_sizes, int n_in,
                              void* d_out, int out_size, void* d_ws, size_t ws_size,
                              hipStream_t stream)
{
    const int*   ei       = (const int*)  d_in[0];   // edge_index [2,E]
    const float* edge_rep = (const float*)d_in[1];   // [E,192]
    const float* x        = (const float*)d_in[2];   // [N,128]
    const float* proto    = (const float*)d_in[4];   // [N,128]
    const float* nf       = (const float*)d_in[5];   // [N,64]
    const float* lin1_W   = (const float*)d_in[6];
    const float* lin1_b   = (const float*)d_in[7];
    const float* lin2_W   = (const float*)d_in[8];
    const float* lin2_b   = (const float*)d_in[9];
    const float* hc1_W    = (const float*)d_in[10];
    const float* hc1_b    = (const float*)d_in[11];
    const float* hc2_W    = (const float*)d_in[12];
    const float* hc2_b    = (const float*)d_in[13];
    float* out = (float*)d_out;

    const int S = 2 * NE;

    // ---- small scratch in ws ----
    char* ws = (char*)d_ws;
    float* nw   = (float*)(ws);                 // 20000 f32 (pad 81920 B)
    float* Dinv = (float*)(ws + 81920);         // 320000 f32 (1.28 MB)
    int*   deg  = (int*)  (ws + 1363968);       // 20000 i32
    int*   off  = (int*)  (ws + 1445888);       // 20001 i32
    int*   cur  = (int*)  (ws + 1527808);       // 20000 i32
    float* Binv = (float*)(ws + 1609728);       // 20000 f32
    float* e2   = (float*)(ws + 1691648);       // 20000x128 f32 (10.24 MB)

    // ---- big scratch inside d_out (fully overwritten by out_kernel last) ----
    char* ob = (char*)d_out;
    float* agg   = (float*)(ob);                // 20000x256 f32 (20.48 MB)
    float* e1    = (float*)(ob + 20971520);     // 20000x256 f32 (20.48 MB)
    float* h     = (float*)(ob + 41943040);     // 20000x128 f32 (10.24 MB)
    int*   csr_j = (int*)  (ob + 52428800);     // 640000 i32 (2.56 MB)
    int*   csr_o = (int*)  (ob + 54988800);     // 640000 i32 (2.56 MB)

    hipMemsetAsync(deg, 0, NN * sizeof(int), stream);
    hipMemsetAsync(cur, 0, NN * sizeof(int), stream);

    // 1) h = relu([x|proto] @ lin1_W + lin1_b)      [20000,256]@[256,128]
    gemm_f32<true, true, true><<<dim3(313, 2), 128, 0, stream>>>(
        x, proto, lin1_W, lin1_b, h, NN, 128, 256);

    // 2) nw = sigmoid(h @ lin2_W + lin2_b)
    nw_kernel<<<5000, 256, 0, stream>>>(h, lin2_W, lin2_b, nw);

    // 3) degree histogram
    deg_kernel<<<(S + 255) / 256, 256, 0, stream>>>(ei, deg);

    // 4) Dinv per edge
    dinv_kernel<<<(NE + 255) / 256, 256, 0, stream>>>(ei, nw, Dinv);

    // 5) offsets + Binv
    scan_kernel<<<1, 1024, 0, stream>>>(deg, off, Binv);

    // 6) CSR fill
    fill_kernel<<<(S + 255) / 256, 256, 0, stream>>>(ei, off, cur, csr_j, csr_o);

    // 7) agg0
    agg0_kernel<<<NN, 256, 0, stream>>>(csr_j, csr_o, off, Binv, edge_rep, nf, agg);

    // 8) e1 = agg0 @ hc1_W                          [20000,256]@[256,256]
    gemm_f32<false, false, false><<<dim3(313, 4), 128, 0, stream>>>(
        agg, nullptr, hc1_W, nullptr, e1, NN, 256, 256);

    // 9) agg1
    agg1_kernel<<<NN, 256, 0, stream>>>(csr_j, csr_o, off, Binv, Dinv, e1, hc1_b, agg);

    // 10) e2 = agg1 @ hc2_W                         [20000,256]@[256,128]
    gemm_f32<false, false, false><<<dim3(313, 2), 128, 0, stream>>>(
        agg, nullptr, hc2_W, nullptr, e2, NN, 128, 256);

    // 11) final per-edge output (fully overwrites d_out)
    out_kernel<<<NE / 8, 256, 0, stream>>>(e2, Dinv, ei, hc2_b, out);
}